// Round 8
// baseline (83.142 us; speedup 1.0000x reference)
//
#include <hip/hip_runtime.h>
#include <float.h>

#define FH 64
#define FW 64
#define FC 256
#define NB 4
#define NR 128
#define NREG 32
#define POOLH 3
#define POOLW 3
#define IOU_THR 0.4f
#define NCELL (POOLH * POOLW)
#define MAXPIX 160   // max cell pixels: last band <= 12 -> 12*12=144, padded
#define SLAB_BYTES (FH * FW * FC * 4)   // 4 MB per batch

#define POOLED_ELEMS (NB * NREG * NCELL * FC)

// Python floor-division semantics for /2 on possibly-negative ints.
__device__ inline void fix_axis(int mn, int mx, int ps, int fs, int& omin, int& omax) {
    int pad = ps - (mx - mn);
    bool fix_min = mn < (pad >> 1);
    bool fix_max = (fs - mx) < ((1 + pad) >> 1);
    bool sym = (pad > 0) && !(fix_min || fix_max);
    omin = sym ? (mn - (pad >> 1)) : mn;
    omax = sym ? (mx + ((1 + pad) >> 1)) : mx;
    if ((pad > 0) && fix_min) { omin = 0; omax = ps; }
    if ((pad > 0) && fix_max) { omin = fs - ps; omax = fs; }
}

__device__ inline float4 max4(float4 a, float4 b) {
    float4 o;
    o.x = fmaxf(a.x, b.x); o.y = fmaxf(a.y, b.y);
    o.z = fmaxf(a.z, b.z); o.w = fmaxf(a.w, b.w);
    return o;
}

// Broadcast lane `lane`'s 64-bit value to all lanes (lane must be wave-uniform).
__device__ inline unsigned long long readlane64(unsigned long long v, int lane) {
    unsigned lo = (unsigned)__builtin_amdgcn_readlane((int)(unsigned)v, lane);
    unsigned hi = (unsigned)__builtin_amdgcn_readlane((int)(unsigned)(v >> 32), lane);
    return ((unsigned long long)hi << 32) | lo;
}

// One block per (region, pool-cell). Phase 0 streams the batch's feature slab
// into L2 at coalesced-load BW (global_load_lds into throwaway LDS scratch,
// overlapped with the NMS row-build). Then bitmask NMS + early-exit scan
// resolve, float4 pooling with 8 loads in flight (now L2 hits).
__global__ __launch_bounds__(256) void fused_kernel(
    const float* __restrict__ features,  // (B, H, W, C)
    const float* __restrict__ roi,       // (B, R, 4)
    float* __restrict__ out)             // pooled (B,32,3,3,C) ++ roi_clipped (B,32,4)
{
    // XCD batch-affinity swizzle: consecutive hw block IDs round-robin the 8
    // XCDs (id & 7). Batch b's 288 blocks land on XCD pair {2b, 2b+1} so its
    // 4 MB feature slab stays resident in 8 MB of paired L2.
    const int hwid = blockIdx.x;
    const int b = (hwid >> 1) & 3;
    const int j = (hwid >> 3) * 2 + (hwid & 1);   // 0..287 within batch
    const int r = j / NCELL;                      // region 0..31
    const int cell = j - r * NCELL;               // 0..8
    const int ci = cell / POOLW, cj = cell - ci * POOLW;
    const int reg = b * NREG + r;
    const int tid = threadIdx.x;
    const int wid = tid >> 6;                     // wave id = pixel group
    const int lane = tid & 63;

    __shared__ float sx1[NR], sy1[NR], sx2[NR], sy2[NR], sarea[NR];
    __shared__ unsigned long long smask[NR][2];   // [64..127][0] never written/read
    __shared__ int spix[MAXPIX];
    __shared__ float4 sred[4][64];
    __shared__ char pfscratch[1024];              // prefetch sink (never read)

    // Load this batch's boxes
    if (tid < NR) {
        const float4 bx = *(const float4*)(roi + ((size_t)b * NR + tid) * 4);
        sx1[tid] = bx.x; sy1[tid] = bx.y;
        sx2[tid] = bx.x + bx.z; sy2[tid] = bx.y + bx.w;
        sarea[tid] = bx.z * bx.w;
    }
    __syncthreads();

    // Phase 0: stream slab b into L2. Blocks j<256 each cover a distinct
    // 16 KB chunk (4 iters x 256 threads x 16 B). The LDS destination is a
    // throwaway scratch (wave-uniform base + lane*16 per HW semantics); the
    // useful effect is the cache fill. Issued before row-build so the HBM
    // stream overlaps NMS VALU work; the pre-resolve barrier drains it.
    if (j < 256) {
        const char* gbase = (const char*)features
                          + (size_t)b * SLAB_BYTES + (size_t)j * 16384 + (size_t)tid * 16;
        #pragma unroll
        for (int it = 0; it < 4; ++it) {
            __builtin_amdgcn_global_load_lds(
                (const __attribute__((address_space(1))) void*)(gbase + it * 4096),
                (__attribute__((address_space(3))) void*)pfscratch, 16, 0, 0);
        }
    }

    // Row-build. Wave 0: rows 0..63 half 0; wave 2: rows 0..63 half 1;
    // wave 3: rows 64..127 half 1. Wave 1's rows (64..127, half 0) are
    // provably all zero (no j>p with j<64, p>=64) and never read: skip.
    if (wid != 1) {
        const int p = tid & 127;
        const int half = tid >> 7;
        const int j0 = half << 6;
        const float px1 = sx1[p], py1 = sy1[p], px2 = sx2[p], py2 = sy2[p], pa = sarea[p];
        unsigned long long m = 0ull;
        #pragma unroll 8
        for (int t = 0; t < 64; ++t) {
            const int jj = j0 + t;
            float iw = fmaxf(fminf(px2, sx2[jj]) - fmaxf(px1, sx1[jj]), 0.0f);
            float ih = fmaxf(fminf(py2, sy2[jj]) - fmaxf(py1, sy1[jj]), 0.0f);
            float inter = iw * ih;
            bool sup = (jj > p) && (inter > IOU_THR * (pa + sarea[jj] - inter));
            m |= ((unsigned long long)sup) << t;
        }
        smask[p][half] = m;
    }
    __syncthreads();

    // All-wave resolve with early exit: scan kept bits in ascending order
    // (a box still set when reached is final-kept); stop at rank r.
    const unsigned long long aLo = smask[lane][0];       // row lane, bits [0,64)
    const unsigned long long aHi = smask[lane][1];       // row lane, bits [64,128)
    const unsigned long long bHi = smask[lane + 64][1];  // row lane+64, bits [64,128)

    int idx = NR - 1;
    {
        unsigned long long k1 = ~0ull;
        int cnt = 0;
        bool done = false;
        unsigned long long cur = ~0ull;      // half-0 candidates
        while (cur && cnt <= r) {
            int p = __ffsll((unsigned long long)cur) - 1;
            if (cnt == r) { idx = p; done = true; break; }
            ++cnt;
            int ps = __builtin_amdgcn_readfirstlane(p);
            unsigned long long m0 = readlane64(aLo, ps);
            unsigned long long m1 = readlane64(aHi, ps);
            cur = (cur & (cur - 1)) & ~m0;
            k1 &= ~m1;
        }
        if (!done) {
            cur = k1;
            while (cur && cnt <= r) {
                int p = __ffsll((unsigned long long)cur) - 1;
                if (cnt == r) { idx = 64 + p; break; }
                ++cnt;
                int ps = __builtin_amdgcn_readfirstlane(p);
                unsigned long long m1 = readlane64(bHi, ps);
                cur = (cur & (cur - 1)) & ~m1;
            }
        }
    }

    // Clip (all lanes, wave-uniform; sx2 = x1+w exactly matches reference x+w).
    int xmn, xmx, ymn, ymx;
    {
        float x1 = sx1[idx], y1 = sy1[idx], x2f = sx2[idx], y2f = sy2[idx];
        int x_min = (int)fmaxf(0.0f, x1);
        int y_min = (int)fmaxf(0.0f, y1);
        int x_max = (int)fminf((float)FW, x2f);
        int y_max = (int)fminf((float)FH, y2f);
        fix_axis(x_min, x_max, POOLW, FW, xmn, xmx);
        fix_axis(y_min, y_max, POOLH, FH, ymn, ymx);
    }
    if (tid == 0 && cell == 0) {
        float* orc = out + POOLED_ELEMS + ((size_t)reg) * 4;
        orc[0] = (float)xmn;
        orc[1] = (float)ymn;
        orc[2] = (float)(xmx - xmn);
        orc[3] = (float)(ymx - ymn);
    }

    // Cell bounds (registers, all threads agree)
    const int x = xmn, y = ymn, w = xmx - xmn, h = ymx - ymn;
    const int hh = h / POOLH;
    const int ww = w / POOLW;
    const int r0 = y + ci * hh;
    const int r1 = (ci < POOLH - 1) ? (y + (ci + 1) * hh) : (y + h);
    const int c0 = x + cj * ww;
    const int c1 = (cj < POOLW - 1) ? (x + (cj + 1) * ww) : (x + w);
    const int ncols = c1 - c0;
    const int n = (r1 - r0) * ncols;          // 1..144

    // Self-owned pixel offsets: wave g reads only slots k ≡ g (mod 4); lane t
    // of wave g writes exactly k = g + 4t -> intra-wave dependency, no barrier.
    {
        const int k0i = wid + 4 * lane;
        if (k0i < n) {
            int q = k0i / ncols;
            int cc = k0i - q * ncols;
            spix[k0i] = ((r0 + q) * FW + (c0 + cc)) * FC;
        }
    }

    // Pooling: lane owns channels [4*lane, 4*lane+4). Wave g takes pixels
    // k = g, g+4, ...; batches of 8 keep 8 loads in flight.
    const float* fbase = features + (size_t)b * FH * FW * FC;
    const float4 negv = {-FLT_MAX, -FLT_MAX, -FLT_MAX, -FLT_MAX};
    float4 m0 = negv, m1 = negv, m2 = negv, m3 = negv;
    float4 m4 = negv, m5 = negv, m6 = negv, m7 = negv;
    int k = wid;
    for (; k + 28 < n; k += 32) {
        int o0 = spix[k],      o1 = spix[k + 4],  o2 = spix[k + 8],  o3 = spix[k + 12];
        int o4 = spix[k + 16], o5 = spix[k + 20], o6 = spix[k + 24], o7 = spix[k + 28];
        float4 v0 = ((const float4*)(fbase + o0))[lane];
        float4 v1 = ((const float4*)(fbase + o1))[lane];
        float4 v2 = ((const float4*)(fbase + o2))[lane];
        float4 v3 = ((const float4*)(fbase + o3))[lane];
        float4 v4 = ((const float4*)(fbase + o4))[lane];
        float4 v5 = ((const float4*)(fbase + o5))[lane];
        float4 v6 = ((const float4*)(fbase + o6))[lane];
        float4 v7 = ((const float4*)(fbase + o7))[lane];
        m0 = max4(m0, v0); m1 = max4(m1, v1); m2 = max4(m2, v2); m3 = max4(m3, v3);
        m4 = max4(m4, v4); m5 = max4(m5, v5); m6 = max4(m6, v6); m7 = max4(m7, v7);
    }
    for (; k + 12 < n; k += 16) {
        int o0 = spix[k], o1 = spix[k + 4], o2 = spix[k + 8], o3 = spix[k + 12];
        float4 v0 = ((const float4*)(fbase + o0))[lane];
        float4 v1 = ((const float4*)(fbase + o1))[lane];
        float4 v2 = ((const float4*)(fbase + o2))[lane];
        float4 v3 = ((const float4*)(fbase + o3))[lane];
        m0 = max4(m0, v0); m1 = max4(m1, v1); m2 = max4(m2, v2); m3 = max4(m3, v3);
    }
    for (; k < n; k += 4) {
        float4 v = ((const float4*)(fbase + spix[k]))[lane];
        m0 = max4(m0, v);
    }
    m0 = max4(max4(m0, m1), max4(m2, m3));
    m4 = max4(max4(m4, m5), max4(m6, m7));
    sred[wid][lane] = max4(m0, m4);
    __syncthreads();

    // Final reduce over the 4 waves; coalesced float4 store.
    if (tid < 64) {
        float4 a = max4(max4(sred[0][tid], sred[1][tid]),
                        max4(sred[2][tid], sred[3][tid]));
        float4* ob = (float4*)(out + ((size_t)reg * NCELL + cell) * FC);
        ob[tid] = a;
    }
}

extern "C" void kernel_launch(void* const* d_in, const int* in_sizes, int n_in,
                              void* d_out, int out_size, void* d_ws, size_t ws_size,
                              hipStream_t stream) {
    const float* features = (const float*)d_in[0];  // (4, 64, 64, 256) f32
    const float* roi = (const float*)d_in[1];       // (4, 128, 4) f32
    float* out = (float*)d_out;                     // 294912 + 512 f32 elems
    (void)in_sizes; (void)n_in; (void)out_size; (void)d_ws; (void)ws_size;

    fused_kernel<<<NB * NREG * NCELL, 256, 0, stream>>>(features, roi, out);
}

// Round 9
// 81.608 us; speedup vs baseline: 1.0188x; 1.0188x over previous
//
#include <hip/hip_runtime.h>
#include <float.h>

#define FH 64
#define FW 64
#define FC 256
#define NB 4
#define NR 128
#define NREG 32
#define POOLH 3
#define POOLW 3
#define IOU_THR 0.4f
#define NCELL (POOLH * POOLW)
#define MAXPIX 144   // max cell pixels: h,w<=32 -> last band <=12 -> 12*12

#define POOLED_ELEMS (NB * NREG * NCELL * FC)

// Python floor-division semantics for /2 on possibly-negative ints.
__device__ inline void fix_axis(int mn, int mx, int ps, int fs, int& omin, int& omax) {
    int pad = ps - (mx - mn);
    bool fix_min = mn < (pad >> 1);
    bool fix_max = (fs - mx) < ((1 + pad) >> 1);
    bool sym = (pad > 0) && !(fix_min || fix_max);
    omin = sym ? (mn - (pad >> 1)) : mn;
    omax = sym ? (mx + ((1 + pad) >> 1)) : mx;
    if ((pad > 0) && fix_min) { omin = 0; omax = ps; }
    if ((pad > 0) && fix_max) { omin = fs - ps; omax = fs; }
}

__device__ inline float4 max4(float4 a, float4 b) {
    float4 o;
    o.x = fmaxf(a.x, b.x); o.y = fmaxf(a.y, b.y);
    o.z = fmaxf(a.z, b.z); o.w = fmaxf(a.w, b.w);
    return o;
}

// Broadcast lane `lane`'s 64-bit value to all lanes (lane must be wave-uniform).
__device__ inline unsigned long long readlane64(unsigned long long v, int lane) {
    unsigned lo = (unsigned)__builtin_amdgcn_readlane((int)(unsigned)v, lane);
    unsigned hi = (unsigned)__builtin_amdgcn_readlane((int)(unsigned)(v >> 32), lane);
    return ((unsigned long long)hi << 32) | lo;
}

// Pool nn pixels (offsets in spixw, LDS) for this lane's 4 channels.
// 16 independent loads in flight to shorten the dependent chain.
__device__ inline float4 pool_pixels(const float* __restrict__ fbase,
                                     const int* spixw, int nn, int lane) {
    const float4 negv = {-FLT_MAX, -FLT_MAX, -FLT_MAX, -FLT_MAX};
    float4 m[16];
    #pragma unroll
    for (int i = 0; i < 16; ++i) m[i] = negv;
    int k = 0;
    for (; k + 15 < nn; k += 16) {
        float4 v[16];
        #pragma unroll
        for (int i = 0; i < 16; ++i)
            v[i] = ((const float4*)(fbase + spixw[k + i]))[lane];
        #pragma unroll
        for (int i = 0; i < 16; ++i) m[i] = max4(m[i], v[i]);
    }
    for (; k + 3 < nn; k += 4) {
        float4 v0 = ((const float4*)(fbase + spixw[k]))[lane];
        float4 v1 = ((const float4*)(fbase + spixw[k + 1]))[lane];
        float4 v2 = ((const float4*)(fbase + spixw[k + 2]))[lane];
        float4 v3 = ((const float4*)(fbase + spixw[k + 3]))[lane];
        m[0] = max4(m[0], v0); m[1] = max4(m[1], v1);
        m[2] = max4(m[2], v2); m[3] = max4(m[3], v3);
    }
    for (; k < nn; ++k)
        m[0] = max4(m[0], ((const float4*)(fbase + spixw[k]))[lane]);
    #pragma unroll
    for (int s = 8; s > 0; s >>= 1)
        for (int i = 0; i < s; ++i) m[i] = max4(m[i], m[i + s]);
    return m[0];
}

// Process one (region,cell): read clipped box from LDS table, build this
// wave's pixel-offset list (intra-wave dep only), pool, store. Also writes
// roi_clipped for cell 0 of each region.
__device__ inline void do_cell(int c, int b, const int (*sbox4)[4], int* spixw,
                               const float* __restrict__ fbase,
                               float* __restrict__ out, int lane) {
    const int r = c / NCELL;
    const int cell = c - r * NCELL;
    const int ci = cell / POOLW, cj = cell - ci * POOLW;
    // LDS broadcast reads (same address across lanes)
    const int x = sbox4[r][0], y = sbox4[r][1], w = sbox4[r][2], h = sbox4[r][3];
    const int hh = h / POOLH;
    const int ww = w / POOLW;
    const int r0 = y + ci * hh;
    const int r1 = (ci < POOLH - 1) ? (y + (ci + 1) * hh) : (y + h);
    const int c0 = x + cj * ww;
    const int c1 = (cj < POOLW - 1) ? (x + (cj + 1) * ww) : (x + w);
    const int ncols = c1 - c0;
    const int nn = (r1 - r0) * ncols;    // 1..144

    for (int t = lane; t < nn; t += 64) {
        int q = t / ncols;
        int cc = t - q * ncols;
        spixw[t] = ((r0 + q) * FW + (c0 + cc)) * FC;
    }
    // intra-wave write->read only: no barrier needed

    float4 a = pool_pixels(fbase, spixw, nn, lane);
    ((float4*)(out + ((size_t)(b * NREG + r) * NCELL + cell) * FC))[lane] = a;

    if (cell == 0 && lane < 4) {
        int v = (lane == 0) ? x : (lane == 1) ? y : (lane == 2) ? w : h;
        out[POOLED_ELEMS + (size_t)(b * NREG + r) * 4 + lane] = (float)v;
    }
}

// Grid = 256 blocks (one per CU), 4 waves each. Block owns 4-5 cells of one
// batch; each WAVE pools a whole cell (no cross-wave reduce). NMS resolved
// once per block (wave 0, all-32-rank single pass). 3 barriers total.
__global__ __launch_bounds__(256, 1) void fused_kernel(
    const float* __restrict__ features,  // (B, H, W, C)
    const float* __restrict__ roi,       // (B, R, 4)
    float* __restrict__ out)             // pooled (B,32,3,3,C) ++ roi_clipped (B,32,4)
{
    // XCD batch-affinity swizzle: hw ids round-robin XCDs (id & 7); batch b's
    // 64 blocks land on XCD pair {2b,2b+1} so its slab stays in paired L2.
    const int hwid = blockIdx.x;
    const int b = (hwid >> 1) & 3;
    const int j = (hwid >> 3) * 2 + (hwid & 1);   // 0..63 within batch
    const int tid = threadIdx.x;
    const int wid = tid >> 6;
    const int lane = tid & 63;
    const int g = j * 4 + wid;                    // wave index in batch, 0..255

    __shared__ float sx1[NR], sy1[NR], sx2[NR], sy2[NR], sarea[NR];
    __shared__ unsigned long long smask[NR][2];   // [64..127][0] never written/read
    __shared__ int sbox4[NREG][4];                // clipped {x,y,w,h} per region
    __shared__ int spix[4][MAXPIX];               // per-wave pixel offsets

    // Load this batch's boxes
    if (tid < NR) {
        const float4 bx = *(const float4*)(roi + ((size_t)b * NR + tid) * 4);
        sx1[tid] = bx.x; sy1[tid] = bx.y;
        sx2[tid] = bx.x + bx.z; sy2[tid] = bx.y + bx.w;
        sarea[tid] = bx.z * bx.w;
    }
    __syncthreads();

    // Row-build. Waves 0,2,3 build rows (0..63 h0, 0..63 h1, 64..127 h1);
    // wave 1's rows (64..127 h0) are provably zero and never read: skip.
    if (wid != 1) {
        const int p = tid & 127;
        const int half = tid >> 7;
        const int j0 = half << 6;
        const float px1 = sx1[p], py1 = sy1[p], px2 = sx2[p], py2 = sy2[p], pa = sarea[p];
        unsigned long long m = 0ull;
        #pragma unroll 8
        for (int t = 0; t < 64; ++t) {
            const int jj = j0 + t;
            float iw = fmaxf(fminf(px2, sx2[jj]) - fmaxf(px1, sx1[jj]), 0.0f);
            float ih = fmaxf(fminf(py2, sy2[jj]) - fmaxf(py1, sy1[jj]), 0.0f);
            float inter = iw * ih;
            bool sup = (jj > p) && (inter > IOU_THR * (pa + sarea[jj] - inter));
            m |= ((unsigned long long)sup) << t;
        }
        smask[p][half] = m;
    }
    __syncthreads();

    // Wave 0: single-pass scan capturing ALL 32 ranks (lane t records rank t),
    // then lanes 0..31 clip their region into the LDS table.
    if (wid == 0) {
        const unsigned long long aLo = smask[lane][0];
        const unsigned long long aHi = smask[lane][1];
        const unsigned long long bHi = smask[lane + 64][1];

        int myidx = NR - 1;   // lane t: region t's kept idx (pad 127)
        {
            unsigned long long k1 = ~0ull;
            int cnt = 0;
            unsigned long long cur = ~0ull;
            while (cur && cnt < NREG) {
                int p = __ffsll((unsigned long long)cur) - 1;
                if (cnt == lane) myidx = p;       // per-lane capture
                ++cnt;
                int ps = __builtin_amdgcn_readfirstlane(p);
                cur = (cur & (cur - 1)) & ~readlane64(aLo, ps);
                k1 &= ~readlane64(aHi, ps);
            }
            cur = k1;
            while (cur && cnt < NREG) {
                int p = __ffsll((unsigned long long)cur) - 1;
                if (cnt == lane) myidx = 64 + p;
                ++cnt;
                int ps = __builtin_amdgcn_readfirstlane(p);
                cur = (cur & (cur - 1)) & ~readlane64(bHi, ps);
            }
        }
        if (lane < NREG) {
            // Clip region `lane` (sx2 = x1+w exactly matches reference x+w).
            float x1 = sx1[myidx], y1 = sy1[myidx], x2f = sx2[myidx], y2f = sy2[myidx];
            int x_min = (int)fmaxf(0.0f, x1);
            int y_min = (int)fmaxf(0.0f, y1);
            int x_max = (int)fminf((float)FW, x2f);
            int y_max = (int)fminf((float)FH, y2f);
            int xmn, xmx, ymn, ymx;
            fix_axis(x_min, x_max, POOLW, FW, xmn, xmx);
            fix_axis(y_min, y_max, POOLH, FH, ymn, ymx);
            sbox4[lane][0] = xmn;
            sbox4[lane][1] = ymn;
            sbox4[lane][2] = xmx - xmn;
            sbox4[lane][3] = ymx - ymn;
        }
    }
    __syncthreads();

    // Pool: wave g handles cell g; blocks j<32 give wave 0 the extra cell
    // 256+j (288 cells per batch = 64 blocks x 4.5).
    const float* fbase = features + (size_t)b * FH * FW * FC;
    do_cell(g, b, sbox4, spix[wid], fbase, out, lane);
    if (wid == 0 && j < NREG)
        do_cell(256 + j, b, sbox4, spix[0], fbase, out, lane);
}

extern "C" void kernel_launch(void* const* d_in, const int* in_sizes, int n_in,
                              void* d_out, int out_size, void* d_ws, size_t ws_size,
                              hipStream_t stream) {
    const float* features = (const float*)d_in[0];  // (4, 64, 64, 256) f32
    const float* roi = (const float*)d_in[1];       // (4, 128, 4) f32
    float* out = (float*)d_out;                     // 294912 + 512 f32 elems
    (void)in_sizes; (void)n_in; (void)out_size; (void)d_ws; (void)ws_size;

    fused_kernel<<<NB * 64, 256, 0, stream>>>(features, roi, out);
}